// Round 6
// baseline (578.083 us; speedup 1.0000x reference)
//
#include <hip/hip_runtime.h>
#include <hip/hip_bf16.h>

// Problem constants (AdaptiveMobiusLayer): B=4, S=4096, DIM=1024
#define PB 4
#define PS 4096
#define PD 1024
#define ROWS (PB * PS)          // 16384
#define NUM_CYCLES 3
#define BASE_COUPLING 0.1f

typedef __attribute__((ext_vector_type(8))) short bf16x8;
typedef __attribute__((ext_vector_type(4))) float f32x4;

// ---------------- helpers ----------------
__device__ __forceinline__ float geluf(float x) {
    return 0.5f * x * (1.0f + erff(x * 0.70710678118654752440f));
}
__device__ __forceinline__ float sigmf_(float x) {
    return 1.0f / (1.0f + expf(-x));
}
__device__ __forceinline__ uint2 pk4(float4 v) {
    __hip_bfloat16 h[4] = {__float2bfloat16(v.x), __float2bfloat16(v.y),
                           __float2bfloat16(v.z), __float2bfloat16(v.w)};
    return *reinterpret_cast<uint2*>(h);
}
__device__ __forceinline__ float4 axpy4(float4 a, float s, float4 b) {
    return make_float4(fmaf(s, b.x, a.x), fmaf(s, b.y, a.y),
                       fmaf(s, b.z, a.z), fmaf(s, b.w, a.w));
}

// global_load_lds: 16B per lane, LDS dest = wave-uniform base + lane*16
#define GLD_LDS16(gsrc, ldst)                                                        \
    __builtin_amdgcn_global_load_lds(                                                \
        (const __attribute__((address_space(1))) void*)(gsrc),                       \
        (__attribute__((address_space(3))) void*)(ldst), 16, 0, 0)

#define ASM_VMCNT4() asm volatile("s_waitcnt vmcnt(4)" ::: "memory")
#define ASM_VMCNT2() asm volatile("s_waitcnt vmcnt(2)" ::: "memory")
#define ASM_VMCNT0() asm volatile("s_waitcnt vmcnt(0)" ::: "memory")
#define BAR() __builtin_amdgcn_s_barrier()

// ---------------- fused: out=x (f32), outb=bf16(x), partial mean over S ----------------
__global__ __launch_bounds__(256) void copy_mean_kernel(const float* __restrict__ x,
                                                        float* __restrict__ out,
                                                        __hip_bfloat16* __restrict__ outb,
                                                        float* __restrict__ part) {
    int b = blockIdx.x >> 6, sc = blockIdx.x & 63;
    size_t base = ((size_t)b * PS + (size_t)sc * 64) * PD;
    const float4* x4 = reinterpret_cast<const float4*>(x + base);
    float4* o4 = reinterpret_cast<float4*>(out + base);
    uint2* ob = reinterpret_cast<uint2*>(outb + base);
    int t = threadIdx.x;
    float4 acc = make_float4(0.f, 0.f, 0.f, 0.f);
    for (int r = 0; r < 64; ++r) {
        float4 v = x4[r * 256 + t];
        o4[r * 256 + t] = v;
        ob[r * 256 + t] = pk4(v);
        acc.x += v.x; acc.y += v.y; acc.z += v.z; acc.w += v.w;
    }
    reinterpret_cast<float4*>(part + ((size_t)(b * 64 + sc)) * PD)[t] = acc;
}

__global__ __launch_bounds__(256) void mean_stage2(const float* __restrict__ part,
                                                   float* __restrict__ gc) {
    int b = blockIdx.x, t = threadIdx.x;
    float4 s = make_float4(0.f, 0.f, 0.f, 0.f);
    for (int c = 0; c < 64; ++c) {
        float4 v = reinterpret_cast<const float4*>(part + ((size_t)(b * 64 + c)) * PD)[t];
        s.x += v.x; s.y += v.y; s.z += v.z; s.w += v.w;
    }
    s.x *= (1.0f / 4096.0f); s.y *= (1.0f / 4096.0f);
    s.z *= (1.0f / 4096.0f); s.w *= (1.0f / 4096.0f);
    reinterpret_cast<float4*>(gc + (size_t)b * PD)[t] = s;
}

// ---------------- weight transpose+convert: W[K][N] f32 -> Wt[N][K] bf16 ----------------
__global__ __launch_bounds__(256) void transpose_w_kernel(const float* __restrict__ W,
                                                          __hip_bfloat16* __restrict__ Wt,
                                                          int K, int N) {
    __shared__ float t[32][33];
    int k0 = blockIdx.x * 32, n0 = blockIdx.y * 32;
    int tx = threadIdx.x & 31, ty = threadIdx.x >> 5;  // ty 0..7
#pragma unroll
    for (int i = 0; i < 32; i += 8)
        t[ty + i][tx] = W[(size_t)(k0 + ty + i) * N + n0 + tx];
    __syncthreads();
#pragma unroll
    for (int i = 0; i < 32; i += 8)
        Wt[(size_t)(n0 + ty + i) * K + k0 + tx] = __float2bfloat16(t[tx][ty + i]);
}

// ---------------- global context net, parallelized ----------------
__global__ __launch_bounds__(256) void gn1_kernel(const float* __restrict__ gc,
                                                  const float* __restrict__ w1,
                                                  const float* __restrict__ b1,
                                                  float* __restrict__ g1) {
    __shared__ float gcs[1024];
    __shared__ float red[4][64];
    int b = blockIdx.x, j0 = blockIdx.y * 64;
    int t = threadIdx.x, wave = t >> 6, lane = t & 63;
    for (int i = t; i < 1024; i += 256) gcs[i] = gc[(size_t)b * PD + i];
    __syncthreads();
    int j = j0 + lane;
    float a = 0.f;
    int k0 = wave * 256;
    for (int k = k0; k < k0 + 256; ++k) a += gcs[k] * w1[(size_t)k * 512 + j];
    red[wave][lane] = a;
    __syncthreads();
    if (wave == 0) {
        float v = red[0][lane] + red[1][lane] + red[2][lane] + red[3][lane] + b1[j];
        g1[(size_t)b * 512 + j] = geluf(v);
    }
}

__global__ __launch_bounds__(256) void gn2_kernel(const float* __restrict__ g1,
                                                  const float* __restrict__ w2,
                                                  const float* __restrict__ b2,
                                                  float* __restrict__ g2) {
    __shared__ float g1s[512];
    __shared__ float red[4][64];
    int b = blockIdx.x, j0 = blockIdx.y * 64;
    int t = threadIdx.x, wave = t >> 6, lane = t & 63;
    for (int i = t; i < 512; i += 256) g1s[i] = g1[(size_t)b * 512 + i];
    __syncthreads();
    int j = j0 + lane;
    float a = 0.f;
    int k0 = wave * 128;
    for (int k = k0; k < k0 + 128; ++k) a += g1s[k] * w2[(size_t)k * 256 + j];
    red[wave][lane] = a;
    __syncthreads();
    if (wave == 0) {
        float v = red[0][lane] + red[1][lane] + red[2][lane] + red[3][lane] + b2[j];
        g2[(size_t)b * 256 + j] = geluf(v);
    }
}

__global__ __launch_bounds__(256) void gn3_kernel(const float* __restrict__ g2,
                                                  const float* __restrict__ w3,
                                                  const float* __restrict__ b3,
                                                  float* __restrict__ gf) {
    __shared__ float red[256];
    int b = blockIdx.x, t = threadIdx.x;
    red[t] = g2[(size_t)b * 256 + t] * w3[t];
    __syncthreads();
    for (int s = 128; s > 0; s >>= 1) {
        if (t < s) red[t] += red[t + s];
        __syncthreads();
    }
    if (t == 0) gf[b] = sigmf_(red[0] + b3[0]);
}

// ============ 256x256 8-phase MFMA GEMM + bias + GELU ============
// C[m][n] = gelu(sum_k A[m][k]*Wt[n][k] + bias[n]); A: MxK bf16 row-major, Wt: NxK bf16.
// BM=BN=256, BK=64, 512 threads = 8 waves (2M x 4N), wave tile 128x64.
// LDS: A,B tiles [256][64] bf16 (128B rows), double-buffered = 128 KB.
// Swizzle (both sides): phys_byte = logical_byte ^ ((row&7)<<4)  [involution; verified R5]
// K-tile = 4 phases = C-quadrants (mh,nh). Staging units = per-phase row sets:
//   U0=A rows {0-63,128-191}  U1=B rows {0-31,64-95,128-159,192-223}
//   U2=B complement           U3=A rows {64-127,192-255}
// Phase p of tile t issues unit p of tile t+1; counted vmcnt(4) at phases 0,1,3 (never 0).
__global__ __launch_bounds__(512, 2) void gemm256_kernel(
    const __hip_bfloat16* __restrict__ A,
    const __hip_bfloat16* __restrict__ Wt,
    const float* __restrict__ bias,
    __hip_bfloat16* __restrict__ C,
    int K, int N) {
    __shared__ __align__(16) __hip_bfloat16 Als[2][256 * 64];
    __shared__ __align__(16) __hip_bfloat16 Bls[2][256 * 64];
    const int tid = threadIdx.x;
    const int wave = tid >> 6, lane = tid & 63;
    const int nbn = N >> 8;
    const int nwg = gridDim.x;
    const int bid = blockIdx.x;
    const int swz = (bid & 7) * (nwg >> 3) + (bid >> 3);   // nwg % 8 == 0 always here
    const int m0 = (swz / nbn) * 256, n0 = (swz % nbn) * 256;
    const int wr = wave >> 2, wc = wave & 3;
    const int fr = lane & 15, fq = lane >> 4;

    // ---- staging chunk bases (16B units; wave-uniform) ----
    int cbase[8];
    cbase[0] = wave * 64;        cbase[1] = 1024 + wave * 64;          // U0 (A)
    int bb = (wave >> 2) * 512 + (wave & 3) * 64;
    cbase[2] = bb;               cbase[3] = 1024 + bb;                  // U1 (B)
    cbase[4] = 256 + bb;         cbase[5] = 1280 + bb;                  // U2 (B)
    cbase[6] = 512 + wave * 64;  cbase[7] = 1536 + wave * 64;           // U3 (A)
    // ---- per-lane source element offsets (physical chunk -> logical row/k) ----
    int srcoff[8];
#pragma unroll
    for (int i = 0; i < 8; ++i) {
        int c = cbase[i] + lane;
        int P = c * 16;
        int L = P ^ (((P >> 7) & 7) << 4);
        int row = L >> 7;
        int ke = (L & 127) >> 1;
        int tb = (i < 2 || i >= 6) ? m0 : n0;
        srcoff[i] = (tb + row) * K + ke;     // fits in int (< 2^25)
    }
    // ---- per-lane ds_read element offsets (kk=0; kk=1 = ^32) ----
    int aoff[8], boff[4];
#pragma unroll
    for (int fm = 0; fm < 8; ++fm) {
        int row = wr * 128 + fm * 16 + fr;
        int Lb = row * 128 + fq * 16;
        aoff[fm] = (Lb ^ ((row & 7) << 4)) >> 1;
    }
#pragma unroll
    for (int fn = 0; fn < 4; ++fn) {
        int row = wc * 64 + fn * 16 + fr;
        int Lb = row * 128 + fq * 16;
        boff[fn] = (Lb ^ ((row & 7) << 4)) >> 1;
    }

    f32x4 acc[8][4] = {};
    bf16x8 av[4][2], bv[2][2];

#define STAGE(u, bufn, kt) do {                                                      \
    const __hip_bfloat16* sb_ = ((u) < 1 || (u) > 2) ? A : Wt;                       \
    __hip_bfloat16* lb_ = ((u) < 1 || (u) > 2) ? &Als[bufn][0] : &Bls[bufn][0];      \
    GLD_LDS16(sb_ + srcoff[(u)*2 + 0] + (kt), (char*)lb_ + cbase[(u)*2 + 0] * 16);   \
    GLD_LDS16(sb_ + srcoff[(u)*2 + 1] + (kt), (char*)lb_ + cbase[(u)*2 + 1] * 16);   \
} while (0)

#define DS_READS(mh, nh, buf_) do {                                                  \
    _Pragma("unroll") for (int mi = 0; mi < 4; ++mi)                                 \
      _Pragma("unroll") for (int kk = 0; kk < 2; ++kk)                               \
        av[mi][kk] = *(const bf16x8*)(&Als[buf_][0] + (aoff[(mh)*4 + mi] ^ (kk << 5))); \
    _Pragma("unroll") for (int ni = 0; ni < 2; ++ni)                                 \
      _Pragma("unroll") for (int kk = 0; kk < 2; ++kk)                               \
        bv[ni][kk] = *(const bf16x8*)(&Bls[buf_][0] + (boff[(nh)*2 + ni] ^ (kk << 5))); \
} while (0)

#define MFMAS(mh, nh) do {                                                           \
    __builtin_amdgcn_s_setprio(1);                                                   \
    _Pragma("unroll") for (int mi = 0; mi < 4; ++mi)                                 \
      _Pragma("unroll") for (int ni = 0; ni < 2; ++ni)                               \
        _Pragma("unroll") for (int kk = 0; kk < 2; ++kk)                             \
          acc[(mh)*4 + mi][(nh)*2 + ni] = __builtin_amdgcn_mfma_f32_16x16x32_bf16(   \
              av[mi][kk], bv[ni][kk], acc[(mh)*4 + mi][(nh)*2 + ni], 0, 0, 0);       \
    __builtin_amdgcn_s_setprio(0);                                                   \
} while (0)

    // ---- prologue: fully stage tile 0 ----
    STAGE(0, 0, 0); STAGE(1, 0, 0); STAGE(2, 0, 0); STAGE(3, 0, 0);
    ASM_VMCNT0();
    BAR();

    const int nt = K >> 6;
    for (int t = 0; t < nt - 1; ++t) {
        const int buf = t & 1;
        const int nbuf = buf ^ 1;
        const int ktn = (t + 1) << 6;
        // phase 0: quadrant (0,0); stage U0(t+1); vmcnt covers next phase's B1(t)
        DS_READS(0, 0, buf); STAGE(0, nbuf, ktn); MFMAS(0, 0); ASM_VMCNT4(); BAR();
        // phase 1: quadrant (0,1); stage U1(t+1); vmcnt covers A1(t)
        DS_READS(0, 1, buf); STAGE(1, nbuf, ktn); MFMAS(0, 1); ASM_VMCNT4(); BAR();
        // phase 2: quadrant (1,0); stage U2(t+1); no wait needed
        DS_READS(1, 0, buf); STAGE(2, nbuf, ktn); MFMAS(1, 0); BAR();
        // phase 3: quadrant (1,1); stage U3(t+1); vmcnt covers A0,B0(t+1)
        DS_READS(1, 1, buf); STAGE(3, nbuf, ktn); MFMAS(1, 1); ASM_VMCNT4(); BAR();
    }
    {   // ---- last tile: no staging; drain progressively ----
        const int buf = (nt - 1) & 1;
        DS_READS(0, 0, buf); MFMAS(0, 0); ASM_VMCNT2(); BAR();
        DS_READS(0, 1, buf); MFMAS(0, 1); ASM_VMCNT0(); BAR();
        DS_READS(1, 0, buf); MFMAS(1, 0); BAR();
        DS_READS(1, 1, buf); MFMAS(1, 1);
    }

    // ---- epilogue: bias + gelu + bf16 store ----
#pragma unroll
    for (int fm = 0; fm < 8; ++fm) {
#pragma unroll
        for (int fn = 0; fn < 4; ++fn) {
            int n = n0 + wc * 64 + fn * 16 + fr;
            float bs = bias[n];
#pragma unroll
            for (int r = 0; r < 4; ++r) {
                int m = m0 + wr * 128 + fm * 16 + fq * 4 + r;
                C[(size_t)m * N + n] = __float2bfloat16(geluf(acc[fm][fn][r] + bs));
            }
        }
    }
#undef STAGE
#undef DS_READS
#undef MFMAS
}

// ---------------- final layer (256->1) + sigmoid + coupling + twist update ----------------
__global__ __launch_bounds__(256) void tf_update_kernel(
    const __hip_bfloat16* __restrict__ h3,  // ROWS x 256
    const float* __restrict__ w4, const float* __restrict__ b4,
    const float* __restrict__ gf, const float* __restrict__ arp,
    float* __restrict__ out, __hip_bfloat16* __restrict__ outb) {
    const int wid = threadIdx.x >> 6, lane = threadIdx.x & 63;
    const int r = blockIdx.x * 4 + wid;
    const int b = r >> 12;  // S = 4096 rows per batch

    uint2 hv = reinterpret_cast<const uint2*>(h3 + (size_t)r * 256)[lane];
    __hip_bfloat16 hh[4];
    *reinterpret_cast<uint2*>(hh) = hv;
    float4 wv = reinterpret_cast<const float4*>(w4)[lane];
    float p = __bfloat162float(hh[0]) * wv.x + __bfloat162float(hh[1]) * wv.y +
              __bfloat162float(hh[2]) * wv.z + __bfloat162float(hh[3]) * wv.w;
#pragma unroll
    for (int off = 32; off; off >>= 1) p += __shfl_xor(p, off);
    float tf = sigmf_(p + b4[0]);
    float comb = 0.7f * gf[b] + 0.3f * tf;
    float c = BASE_COUPLING + arp[0] * (comb - 0.5f) * 2.0f;

    float4* row4 = reinterpret_cast<float4*>(out + (size_t)r * PD);
    uint2* rb4 = reinterpret_cast<uint2*>(outb + (size_t)r * PD);
    float4 o_r = row4[lane];
    float4 o_i = row4[64 + lane];
    float4 p_r = row4[128 + lane];
    float4 p_i = row4[192 + lane];
    float4 n0 = axpy4(o_r, c, p_r);
    float4 n1 = axpy4(o_i, -c, p_i);
    float4 n2 = axpy4(p_r, -c, o_r);
    float4 n3 = axpy4(p_i, c, o_i);
    row4[lane] = n0;        rb4[lane] = pk4(n0);
    row4[64 + lane] = n1;   rb4[64 + lane] = pk4(n1);
    row4[128 + lane] = n2;  rb4[128 + lane] = pk4(n2);
    row4[192 + lane] = n3;  rb4[192 + lane] = pk4(n3);
}

// ---------------- launch ----------------
extern "C" void kernel_launch(void* const* d_in, const int* in_sizes, int n_in,
                              void* d_out, int out_size, void* d_ws, size_t ws_size,
                              hipStream_t stream) {
    const float* x     = (const float*)d_in[0];
    const float* cn_w1 = (const float*)d_in[1];
    const float* cn_b1 = (const float*)d_in[2];
    const float* cn_w2 = (const float*)d_in[3];
    const float* cn_b2 = (const float*)d_in[4];
    const float* cn_w3 = (const float*)d_in[5];
    const float* cn_b3 = (const float*)d_in[6];
    const float* cn_w4 = (const float*)d_in[7];
    const float* cn_b4 = (const float*)d_in[8];
    const float* gc_w1 = (const float*)d_in[9];
    const float* gc_b1 = (const float*)d_in[10];
    const float* gc_w2 = (const float*)d_in[11];
    const float* gc_b2 = (const float*)d_in[12];
    const float* gc_w3 = (const float*)d_in[13];
    const float* gc_b3 = (const float*)d_in[14];
    const float* ar    = (const float*)d_in[15];

    float* out = (float*)d_out;

    char* ws = (char*)d_ws;
    __hip_bfloat16* h1   = (__hip_bfloat16*)(ws);                      // 32 MB
    __hip_bfloat16* h2   = (__hip_bfloat16*)(ws + ((size_t)32 << 20)); // 16 MB
    __hip_bfloat16* h3   = (__hip_bfloat16*)(ws + ((size_t)48 << 20)); // 8 MB
    __hip_bfloat16* outb = (__hip_bfloat16*)(ws + ((size_t)56 << 20)); // 32 MB
    __hip_bfloat16* wt1  = (__hip_bfloat16*)(ws + ((size_t)88 << 20)); // 2 MB
    __hip_bfloat16* wt2  = (__hip_bfloat16*)(ws + ((size_t)90 << 20)); // 1 MB
    __hip_bfloat16* wt3  = (__hip_bfloat16*)(ws + ((size_t)91 << 20)); // 0.25 MB
    float* part          = (float*)(ws + ((size_t)91 << 20) + (1 << 18)); // 4*64*1024 f32
    float* gc            = part + 4 * 64 * PD;
    float* g1            = gc + 4 * PD;
    float* g2            = g1 + 4 * 512;
    float* gf            = g2 + 4 * 256;

    transpose_w_kernel<<<dim3(32, 32), 256, 0, stream>>>(cn_w1, wt1, 1024, 1024);
    transpose_w_kernel<<<dim3(32, 16), 256, 0, stream>>>(cn_w2, wt2, 1024, 512);
    transpose_w_kernel<<<dim3(16, 8), 256, 0, stream>>>(cn_w3, wt3, 512, 256);

    copy_mean_kernel<<<256, 256, 0, stream>>>(x, out, outb, part);
    mean_stage2<<<PB, 256, 0, stream>>>(part, gc);

    gn1_kernel<<<dim3(PB, 8), 256, 0, stream>>>(gc, gc_w1, gc_b1, g1);
    gn2_kernel<<<dim3(PB, 4), 256, 0, stream>>>(g1, gc_w2, gc_b2, g2);
    gn3_kernel<<<PB, 256, 0, stream>>>(g2, gc_w3, gc_b3, gf);

    for (int cyc = 0; cyc < NUM_CYCLES; ++cyc) {
        gemm256_kernel<<<64 * 4, 512, 0, stream>>>(outb, wt1, cn_b1, h1, 1024, 1024);
        gemm256_kernel<<<64 * 2, 512, 0, stream>>>(h1, wt2, cn_b2, h2, 1024, 512);
        gemm256_kernel<<<64 * 1, 512, 0, stream>>>(h2, wt3, cn_b3, h3, 512, 256);
        tf_update_kernel<<<ROWS / 4, 256, 0, stream>>>(h3, cn_w4, cn_b4, gf, ar, out, outb);
    }
}

// Round 7
// 494.733 us; speedup vs baseline: 1.1685x; 1.1685x over previous
//
#include <hip/hip_runtime.h>
#include <hip/hip_bf16.h>

// Problem constants (AdaptiveMobiusLayer): B=4, S=4096, DIM=1024
#define PB 4
#define PS 4096
#define PD 1024
#define ROWS (PB * PS)          // 16384
#define NUM_CYCLES 3
#define BASE_COUPLING 0.1f

typedef __attribute__((ext_vector_type(8))) short bf16x8;
typedef __attribute__((ext_vector_type(4))) float f32x4;

// ---------------- helpers ----------------
__device__ __forceinline__ float geluf(float x) {
    return 0.5f * x * (1.0f + erff(x * 0.70710678118654752440f));
}
__device__ __forceinline__ float sigmf_(float x) {
    return 1.0f / (1.0f + expf(-x));
}
__device__ __forceinline__ uint2 pk4(float4 v) {
    __hip_bfloat16 h[4] = {__float2bfloat16(v.x), __float2bfloat16(v.y),
                           __float2bfloat16(v.z), __float2bfloat16(v.w)};
    return *reinterpret_cast<uint2*>(h);
}
__device__ __forceinline__ float4 axpy4(float4 a, float s, float4 b) {
    return make_float4(fmaf(s, b.x, a.x), fmaf(s, b.y, a.y),
                       fmaf(s, b.z, a.z), fmaf(s, b.w, a.w));
}

// global_load_lds: 16B per lane, LDS dest = wave-uniform base + lane*16
#define GLD_LDS16(gsrc, ldst)                                                        \
    __builtin_amdgcn_global_load_lds(                                                \
        (const __attribute__((address_space(1))) void*)(gsrc),                       \
        (__attribute__((address_space(3))) void*)(ldst), 16, 0, 0)

// ---------------- fused: out=x (f32), outb=bf16(x), partial mean over S ----------------
__global__ __launch_bounds__(256) void copy_mean_kernel(const float* __restrict__ x,
                                                        float* __restrict__ out,
                                                        __hip_bfloat16* __restrict__ outb,
                                                        float* __restrict__ part) {
    int b = blockIdx.x >> 6, sc = blockIdx.x & 63;
    size_t base = ((size_t)b * PS + (size_t)sc * 64) * PD;
    const float4* x4 = reinterpret_cast<const float4*>(x + base);
    float4* o4 = reinterpret_cast<float4*>(out + base);
    uint2* ob = reinterpret_cast<uint2*>(outb + base);
    int t = threadIdx.x;
    float4 acc = make_float4(0.f, 0.f, 0.f, 0.f);
    for (int r = 0; r < 64; ++r) {
        float4 v = x4[r * 256 + t];
        o4[r * 256 + t] = v;
        ob[r * 256 + t] = pk4(v);
        acc.x += v.x; acc.y += v.y; acc.z += v.z; acc.w += v.w;
    }
    reinterpret_cast<float4*>(part + ((size_t)(b * 64 + sc)) * PD)[t] = acc;
}

__global__ __launch_bounds__(256) void mean_stage2(const float* __restrict__ part,
                                                   float* __restrict__ gc) {
    int b = blockIdx.x, t = threadIdx.x;
    float4 s = make_float4(0.f, 0.f, 0.f, 0.f);
    for (int c = 0; c < 64; ++c) {
        float4 v = reinterpret_cast<const float4*>(part + ((size_t)(b * 64 + c)) * PD)[t];
        s.x += v.x; s.y += v.y; s.z += v.z; s.w += v.w;
    }
    s.x *= (1.0f / 4096.0f); s.y *= (1.0f / 4096.0f);
    s.z *= (1.0f / 4096.0f); s.w *= (1.0f / 4096.0f);
    reinterpret_cast<float4*>(gc + (size_t)b * PD)[t] = s;
}

// ---------------- weight transpose+convert: W[K][N] f32 -> Wt[N][K] bf16 ----------------
__global__ __launch_bounds__(256) void transpose_w_kernel(const float* __restrict__ W,
                                                          __hip_bfloat16* __restrict__ Wt,
                                                          int K, int N) {
    __shared__ float t[32][33];
    int k0 = blockIdx.x * 32, n0 = blockIdx.y * 32;
    int tx = threadIdx.x & 31, ty = threadIdx.x >> 5;  // ty 0..7
#pragma unroll
    for (int i = 0; i < 32; i += 8)
        t[ty + i][tx] = W[(size_t)(k0 + ty + i) * N + n0 + tx];
    __syncthreads();
#pragma unroll
    for (int i = 0; i < 32; i += 8)
        Wt[(size_t)(n0 + ty + i) * K + k0 + tx] = __float2bfloat16(t[tx][ty + i]);
}

// ---------------- global context net, parallelized ----------------
__global__ __launch_bounds__(256) void gn1_kernel(const float* __restrict__ gc,
                                                  const float* __restrict__ w1,
                                                  const float* __restrict__ b1,
                                                  float* __restrict__ g1) {
    __shared__ float gcs[1024];
    __shared__ float red[4][64];
    int b = blockIdx.x, j0 = blockIdx.y * 64;
    int t = threadIdx.x, wave = t >> 6, lane = t & 63;
    for (int i = t; i < 1024; i += 256) gcs[i] = gc[(size_t)b * PD + i];
    __syncthreads();
    int j = j0 + lane;
    float a = 0.f;
    int k0 = wave * 256;
    for (int k = k0; k < k0 + 256; ++k) a += gcs[k] * w1[(size_t)k * 512 + j];
    red[wave][lane] = a;
    __syncthreads();
    if (wave == 0) {
        float v = red[0][lane] + red[1][lane] + red[2][lane] + red[3][lane] + b1[j];
        g1[(size_t)b * 512 + j] = geluf(v);
    }
}

__global__ __launch_bounds__(256) void gn2_kernel(const float* __restrict__ g1,
                                                  const float* __restrict__ w2,
                                                  const float* __restrict__ b2,
                                                  float* __restrict__ g2) {
    __shared__ float g1s[512];
    __shared__ float red[4][64];
    int b = blockIdx.x, j0 = blockIdx.y * 64;
    int t = threadIdx.x, wave = t >> 6, lane = t & 63;
    for (int i = t; i < 512; i += 256) g1s[i] = g1[(size_t)b * 512 + i];
    __syncthreads();
    int j = j0 + lane;
    float a = 0.f;
    int k0 = wave * 128;
    for (int k = k0; k < k0 + 128; ++k) a += g1s[k] * w2[(size_t)k * 256 + j];
    red[wave][lane] = a;
    __syncthreads();
    if (wave == 0) {
        float v = red[0][lane] + red[1][lane] + red[2][lane] + red[3][lane] + b2[j];
        g2[(size_t)b * 256 + j] = geluf(v);
    }
}

__global__ __launch_bounds__(256) void gn3_kernel(const float* __restrict__ g2,
                                                  const float* __restrict__ w3,
                                                  const float* __restrict__ b3,
                                                  float* __restrict__ gf) {
    __shared__ float red[256];
    int b = blockIdx.x, t = threadIdx.x;
    red[t] = g2[(size_t)b * 256 + t] * w3[t];
    __syncthreads();
    for (int s = 128; s > 0; s >>= 1) {
        if (t < s) red[t] += red[t + s];
        __syncthreads();
    }
    if (t == 0) gf[b] = sigmf_(red[0] + b3[0]);
}

// ============ 256x256 MFMA GEMM + bias + GELU — read-once fragment plan ============
// C[m][n] = gelu(sum_k A[m][k]*Wt[n][k] + bias[n]); A: MxK bf16 row-major, Wt: NxK bf16.
// BM=BN=256, BK=64, 512 threads = 8 waves (2M x 4N), wave tile 128x64.
// LDS: A,B tiles [256][64] bf16 (128B rows), double-buffered = 128 KB; 1 block/CU.
// Swizzle (both sides, verified R5/R6): phys_byte = logical_byte ^ ((row&7)<<4).
// Per K-tile: 2 phases, EACH FRAGMENT READ ONCE (24 ds_read_b128/wave/K-tile):
//   ph0: read bv[4][2] (B full, 8) + av=A-half0 (8); stage U0,U1(t+1); 32 MFMA (mh=0)
//   ph1: read av=A-half1 (8);                        stage U2,U3(t+1); 32 MFMA (mh=1)
//   __syncthreads() once per K-tile (drain is ~1.5 phases after issue -> latency covered).
// LDS-read ~2300 cyc/CU/K-tile vs MFMA ~2500 cyc -> balanced (was 4600 vs 2500: LDS-bound).
__global__ __launch_bounds__(512, 2) void gemm256_kernel(
    const __hip_bfloat16* __restrict__ A,
    const __hip_bfloat16* __restrict__ Wt,
    const float* __restrict__ bias,
    __hip_bfloat16* __restrict__ C,
    int K, int N) {
    __shared__ __align__(16) __hip_bfloat16 Als[2][256 * 64];
    __shared__ __align__(16) __hip_bfloat16 Bls[2][256 * 64];
    const int tid = threadIdx.x;
    const int wave = tid >> 6, lane = tid & 63;
    const int nbn = N >> 8;
    const int nwg = gridDim.x;
    const int bid = blockIdx.x;
    const int swz = (bid & 7) * (nwg >> 3) + (bid >> 3);   // nwg % 8 == 0 always here
    const int m0 = (swz / nbn) * 256, n0 = (swz % nbn) * 256;
    const int wr = wave >> 2, wc = wave & 3;
    const int fr = lane & 15, fq = lane >> 4;

    // ---- staging chunk bases (16B units; wave-uniform) ----
    int cbase[8];
    cbase[0] = wave * 64;        cbase[1] = 1024 + wave * 64;          // U0 (A)
    int bb = (wave >> 2) * 512 + (wave & 3) * 64;
    cbase[2] = bb;               cbase[3] = 1024 + bb;                  // U1 (B)
    cbase[4] = 256 + bb;         cbase[5] = 1280 + bb;                  // U2 (B)
    cbase[6] = 512 + wave * 64;  cbase[7] = 1536 + wave * 64;           // U3 (A)
    // ---- per-lane source element offsets (physical chunk -> logical row/k) ----
    int srcoff[8];
#pragma unroll
    for (int i = 0; i < 8; ++i) {
        int c = cbase[i] + lane;
        int P = c * 16;
        int L = P ^ (((P >> 7) & 7) << 4);
        int row = L >> 7;
        int ke = (L & 127) >> 1;
        int tb = (i < 2 || i >= 6) ? m0 : n0;
        srcoff[i] = (tb + row) * K + ke;
    }
    // ---- per-lane ds_read element offsets (kk=0; kk=1 = ^32 elements = +64B) ----
    int aoff[8], boff[4];
#pragma unroll
    for (int fm = 0; fm < 8; ++fm) {
        int row = wr * 128 + fm * 16 + fr;
        int Lb = row * 128 + fq * 16;
        aoff[fm] = (Lb ^ ((row & 7) << 4)) >> 1;
    }
#pragma unroll
    for (int fn = 0; fn < 4; ++fn) {
        int row = wc * 64 + fn * 16 + fr;
        int Lb = row * 128 + fq * 16;
        boff[fn] = (Lb ^ ((row & 7) << 4)) >> 1;
    }

    f32x4 acc[8][4] = {};
    bf16x8 av[4][2], bv[4][2];

#define STAGE(u, bufn, kt) do {                                                      \
    const __hip_bfloat16* sb_ = ((u) < 1 || (u) > 2) ? A : Wt;                       \
    __hip_bfloat16* lb_ = ((u) < 1 || (u) > 2) ? &Als[bufn][0] : &Bls[bufn][0];      \
    GLD_LDS16(sb_ + srcoff[(u)*2 + 0] + (kt), (char*)lb_ + cbase[(u)*2 + 0] * 16);   \
    GLD_LDS16(sb_ + srcoff[(u)*2 + 1] + (kt), (char*)lb_ + cbase[(u)*2 + 1] * 16);   \
} while (0)

    // ---- prologue: fully stage tile 0 ----
    STAGE(0, 0, 0); STAGE(1, 0, 0); STAGE(2, 0, 0); STAGE(3, 0, 0);
    __syncthreads();

    const int nt = K >> 6;
    for (int t = 0; t < nt; ++t) {
        const int buf = t & 1;
        const int nbuf = buf ^ 1;
        const int ktn = (t + 1) << 6;
        const bool pf = (t + 1 < nt);
        // ---- phase 0: B full row + A half 0 (each read once) ----
#pragma unroll
        for (int ni = 0; ni < 4; ++ni)
#pragma unroll
            for (int kk = 0; kk < 2; ++kk)
                bv[ni][kk] = *(const bf16x8*)(&Bls[buf][0] + (boff[ni] ^ (kk << 5)));
#pragma unroll
        for (int mi = 0; mi < 4; ++mi)
#pragma unroll
            for (int kk = 0; kk < 2; ++kk)
                av[mi][kk] = *(const bf16x8*)(&Als[buf][0] + (aoff[mi] ^ (kk << 5)));
        if (pf) { STAGE(0, nbuf, ktn); STAGE(1, nbuf, ktn); }
        __builtin_amdgcn_s_setprio(1);
#pragma unroll
        for (int kk = 0; kk < 2; ++kk)
#pragma unroll
            for (int mi = 0; mi < 4; ++mi)
#pragma unroll
                for (int ni = 0; ni < 4; ++ni)
                    acc[mi][ni] = __builtin_amdgcn_mfma_f32_16x16x32_bf16(
                        av[mi][kk], bv[ni][kk], acc[mi][ni], 0, 0, 0);
        __builtin_amdgcn_s_setprio(0);
        // ---- phase 1: A half 1 (bv reused from registers) ----
#pragma unroll
        for (int mi = 0; mi < 4; ++mi)
#pragma unroll
            for (int kk = 0; kk < 2; ++kk)
                av[mi][kk] = *(const bf16x8*)(&Als[buf][0] + (aoff[4 + mi] ^ (kk << 5)));
        if (pf) { STAGE(2, nbuf, ktn); STAGE(3, nbuf, ktn); }
        __builtin_amdgcn_s_setprio(1);
#pragma unroll
        for (int kk = 0; kk < 2; ++kk)
#pragma unroll
            for (int mi = 0; mi < 4; ++mi)
#pragma unroll
                for (int ni = 0; ni < 4; ++ni)
                    acc[4 + mi][ni] = __builtin_amdgcn_mfma_f32_16x16x32_bf16(
                        av[mi][kk], bv[ni][kk], acc[4 + mi][ni], 0, 0, 0);
        __builtin_amdgcn_s_setprio(0);
        __syncthreads();   // drains vmcnt+lgkm; tile t+1 staged & buffers safe
    }

    // ---- epilogue: bias + gelu + bf16 store ----
#pragma unroll
    for (int fm = 0; fm < 8; ++fm) {
#pragma unroll
        for (int fn = 0; fn < 4; ++fn) {
            int n = n0 + wc * 64 + fn * 16 + fr;
            float bs = bias[n];
#pragma unroll
            for (int r = 0; r < 4; ++r) {
                int m = m0 + wr * 128 + fm * 16 + fq * 4 + r;
                C[(size_t)m * N + n] = __float2bfloat16(geluf(acc[fm][fn][r] + bs));
            }
        }
    }
#undef STAGE
}

// ---------------- final layer (256->1) + sigmoid + coupling + twist update ----------------
__global__ __launch_bounds__(256) void tf_update_kernel(
    const __hip_bfloat16* __restrict__ h3,  // ROWS x 256
    const float* __restrict__ w4, const float* __restrict__ b4,
    const float* __restrict__ gf, const float* __restrict__ arp,
    float* __restrict__ out, __hip_bfloat16* __restrict__ outb) {
    const int wid = threadIdx.x >> 6, lane = threadIdx.x & 63;
    const int r = blockIdx.x * 4 + wid;
    const int b = r >> 12;  // S = 4096 rows per batch

    uint2 hv = reinterpret_cast<const uint2*>(h3 + (size_t)r * 256)[lane];
    __hip_bfloat16 hh[4];
    *reinterpret_cast<uint2*>(hh) = hv;
    float4 wv = reinterpret_cast<const float4*>(w4)[lane];
    float p = __bfloat162float(hh[0]) * wv.x + __bfloat162float(hh[1]) * wv.y +
              __bfloat162float(hh[2]) * wv.z + __bfloat162float(hh[3]) * wv.w;
#pragma unroll
    for (int off = 32; off; off >>= 1) p += __shfl_xor(p, off);
    float tf = sigmf_(p + b4[0]);
    float comb = 0.7f * gf[b] + 0.3f * tf;
    float c = BASE_COUPLING + arp[0] * (comb - 0.5f) * 2.0f;

    float4* row4 = reinterpret_cast<float4*>(out + (size_t)r * PD);
    uint2* rb4 = reinterpret_cast<uint2*>(outb + (size_t)r * PD);
    float4 o_r = row4[lane];
    float4 o_i = row4[64 + lane];
    float4 p_r = row4[128 + lane];
    float4 p_i = row4[192 + lane];
    float4 n0 = axpy4(o_r, c, p_r);
    float4 n1 = axpy4(o_i, -c, p_i);
    float4 n2 = axpy4(p_r, -c, o_r);
    float4 n3 = axpy4(p_i, c, o_i);
    row4[lane] = n0;        rb4[lane] = pk4(n0);
    row4[64 + lane] = n1;   rb4[64 + lane] = pk4(n1);
    row4[128 + lane] = n2;  rb4[128 + lane] = pk4(n2);
    row4[192 + lane] = n3;  rb4[192 + lane] = pk4(n3);
}

// ---------------- launch ----------------
extern "C" void kernel_launch(void* const* d_in, const int* in_sizes, int n_in,
                              void* d_out, int out_size, void* d_ws, size_t ws_size,
                              hipStream_t stream) {
    const float* x     = (const float*)d_in[0];
    const float* cn_w1 = (const float*)d_in[1];
    const float* cn_b1 = (const float*)d_in[2];
    const float* cn_w2 = (const float*)d_in[3];
    const float* cn_b2 = (const float*)d_in[4];
    const float* cn_w3 = (const float*)d_in[5];
    const float* cn_b3 = (const float*)d_in[6];
    const float* cn_w4 = (const float*)d_in[7];
    const float* cn_b4 = (const float*)d_in[8];
    const float* gc_w1 = (const float*)d_in[9];
    const float* gc_b1 = (const float*)d_in[10];
    const float* gc_w2 = (const float*)d_in[11];
    const float* gc_b2 = (const float*)d_in[12];
    const float* gc_w3 = (const float*)d_in[13];
    const float* gc_b3 = (const float*)d_in[14];
    const float* ar    = (const float*)d_in[15];

    float* out = (float*)d_out;

    char* ws = (char*)d_ws;
    __hip_bfloat16* h1   = (__hip_bfloat16*)(ws);                      // 32 MB
    __hip_bfloat16* h2   = (__hip_bfloat16*)(ws + ((size_t)32 << 20)); // 16 MB
    __hip_bfloat16* h3   = (__hip_bfloat16*)(ws + ((size_t)48 << 20)); // 8 MB
    __hip_bfloat16* outb = (__hip_bfloat16*)(ws + ((size_t)56 << 20)); // 32 MB
    __hip_bfloat16* wt1  = (__hip_bfloat16*)(ws + ((size_t)88 << 20)); // 2 MB
    __hip_bfloat16* wt2  = (__hip_bfloat16*)(ws + ((size_t)90 << 20)); // 1 MB
    __hip_bfloat16* wt3  = (__hip_bfloat16*)(ws + ((size_t)91 << 20)); // 0.25 MB
    float* part          = (float*)(ws + ((size_t)91 << 20) + (1 << 18)); // 4*64*1024 f32
    float* gc            = part + 4 * 64 * PD;
    float* g1            = gc + 4 * PD;
    float* g2            = g1 + 4 * 512;
    float* gf            = g2 + 4 * 256;

    transpose_w_kernel<<<dim3(32, 32), 256, 0, stream>>>(cn_w1, wt1, 1024, 1024);
    transpose_w_kernel<<<dim3(32, 16), 256, 0, stream>>>(cn_w2, wt2, 1024, 512);
    transpose_w_kernel<<<dim3(16, 8), 256, 0, stream>>>(cn_w3, wt3, 512, 256);

    copy_mean_kernel<<<256, 256, 0, stream>>>(x, out, outb, part);
    mean_stage2<<<PB, 256, 0, stream>>>(part, gc);

    gn1_kernel<<<dim3(PB, 8), 256, 0, stream>>>(gc, gc_w1, gc_b1, g1);
    gn2_kernel<<<dim3(PB, 4), 256, 0, stream>>>(g1, gc_w2, gc_b2, g2);
    gn3_kernel<<<PB, 256, 0, stream>>>(g2, gc_w3, gc_b3, gf);

    for (int cyc = 0; cyc < NUM_CYCLES; ++cyc) {
        gemm256_kernel<<<64 * 4, 512, 0, stream>>>(outb, wt1, cn_b1, h1, 1024, 1024);
        gemm256_kernel<<<64 * 2, 512, 0, stream>>>(h1, wt2, cn_b2, h2, 1024, 512);
        gemm256_kernel<<<64 * 1, 512, 0, stream>>>(h2, wt3, cn_b3, h3, 512, 256);
        tf_update_kernel<<<ROWS / 4, 256, 0, stream>>>(h3, cn_w4, cn_b4, gf, ar, out, outb);
    }
}